// Round 5
// baseline (286.982 us; speedup 1.0000x reference)
//
#include <hip/hip_runtime.h>
#include <hip/hip_bf16.h>

// GIN 2-layer forward — R19: R18 + 16B/lane gather loads.
// R17's counters showed the gather work is request/latency-bound (8.8% HBM,
// 706 GB/s). uint2->uint4 per-lane loads cover a d256 row with 16 lanes
// (was 32) and a d128 row with 8 lanes (was 16): half the VMEM instructions
// for the same bytes, same 16-slot clamp-predicated structure.
//
//   memset(deg) -> prep (quant x -> u8 + scale | transpose w | degree atomics)
//   block_sum -> scan_blocks2 -> fill
//   h1in  = dequant-gather(x_q)                        [bf16, stride 136]
//   h1q,hscale = quant(relu(relu(h1in@w1+b1)@w2+b2))   [layer1_fused, uint8 out]
//   h2in  = dequant-gather(h1q)                        [bf16, stride 264]
//   out   = log_softmax(relu(h2in@w3+b3)@w4+b4)        [layer2_fused]

typedef __attribute__((ext_vector_type(8))) short bf16x8;
typedef __attribute__((ext_vector_type(4))) float f32x4;

#define GLOAD_LDS16(g, l)                                                     \
    __builtin_amdgcn_global_load_lds(                                         \
        (const __attribute__((address_space(1))) void*)(g),                   \
        (__attribute__((address_space(3))) void*)(l), 16, 0, 0)

static __device__ __forceinline__ unsigned short f2bf(float f) {
    unsigned int u = __float_as_uint(f);
    unsigned int r = (u + 0x7fffu + ((u >> 16) & 1u)) >> 16;
    return (unsigned short)r;
}
static __device__ __forceinline__ float bf2f(unsigned short s) {
    return __uint_as_float(((unsigned int)s) << 16);
}
static __device__ __forceinline__ float bflo(unsigned int u) {
    return __uint_as_float(u << 16);
}
static __device__ __forceinline__ float bfhi(unsigned int u) {
    return __uint_as_float(u & 0xffff0000u);
}

#define S1 136   // 128 + 8 pad (bf16 elems)
#define S2 264   // 256 + 8 pad

// accumulate 8 uint8 lanes (packed uint2) scaled by ss into a[0..7]
// (ubyte extracts fold to v_cvt_f32_ubyte0..3)
static __device__ __forceinline__ void acc8(float* a, uint2 v, float ss) {
    a[0] = fmaf(ss, (float)( v.x        & 0xff), a[0]);
    a[1] = fmaf(ss, (float)((v.x >> 8 ) & 0xff), a[1]);
    a[2] = fmaf(ss, (float)((v.x >> 16) & 0xff), a[2]);
    a[3] = fmaf(ss, (float)( v.x >> 24        ), a[3]);
    a[4] = fmaf(ss, (float)( v.y        & 0xff), a[4]);
    a[5] = fmaf(ss, (float)((v.y >> 8 ) & 0xff), a[5]);
    a[6] = fmaf(ss, (float)((v.y >> 16) & 0xff), a[6]);
    a[7] = fmaf(ss, (float)( v.y >> 24        ), a[7]);
}
// 16-elem variant over a uint4
static __device__ __forceinline__ void acc16(float* a, uint4 v, float ss) {
    acc8(a,     make_uint2(v.x, v.y), ss);
    acc8(a + 8, make_uint2(v.z, v.w), ss);
}

// ---------------- prep: quant x | transpose w1/w2/w3 | degree ----------------
__global__ __launch_bounds__(256) void prep_kernel(
    const float* __restrict__ x,
    unsigned char* __restrict__ x_q, float* __restrict__ xscale,
    const float* __restrict__ w1, const float* __restrict__ w2, const float* __restrict__ w3,
    short* __restrict__ w1t, short* __restrict__ w2t, short* __restrict__ w3t,
    const int* __restrict__ dst, int* __restrict__ deg,
    int M, int E, int cB)
{
    const int b = blockIdx.x;
    const int t = threadIdx.x;
    if (b < cB) {
        // quantize x -> offset u8, per-row (128 elems = 32 threads) absmax scale
        const int i = b * 256 + t;       // global 4-elem group
        const int n4 = M * 32;           // M*128/4
        if (i >= n4) return;
        const float4 v = *(const float4*)(x + (size_t)i * 4);
        float mx = fmaxf(fmaxf(fabsf(v.x), fabsf(v.y)), fmaxf(fabsf(v.z), fabsf(v.w)));
        #pragma unroll
        for (int o2 = 1; o2 < 32; o2 <<= 1)
            mx = fmaxf(mx, __shfl_xor(mx, o2));      // butterfly within 32-lane row group
        const float inv = (mx > 0.f) ? 127.f / mx : 0.f;
        uchar4 o;
        o.x = (unsigned char)(int)(v.x * inv + 128.5f);
        o.y = (unsigned char)(int)(v.y * inv + 128.5f);
        o.z = (unsigned char)(int)(v.z * inv + 128.5f);
        o.w = (unsigned char)(int)(v.w * inv + 128.5f);
        const int row = i >> 5;
        *(uchar4*)(x_q + (size_t)row * 128 + (i & 31) * 4) = o;
        if ((t & 31) == 0) xscale[row] = (mx > 0.f) ? mx * (1.f / 127.f) : 0.f;
        return;
    }
    if (b < cB + 192) {
        const int tb = b - cB;
        const int z = tb >> 6;
        const int rem = tb & 63;
        const int kb = rem & 7;
        const int nb = rem >> 3;
        const float* in; short* outb; int K, ostride;
        if (z == 0)      { in = w1; outb = w1t; K = 128; ostride = S1; }
        else if (z == 1) { in = w2; outb = w2t; K = 256; ostride = S2; }
        else             { in = w3; outb = w3t; K = 256; ostride = S2; }
        const int N = 256;
        const int k0 = kb * 32;
        if (k0 >= K) return;
        const int n0 = nb * 32;
        __shared__ float tile[32][33];
        const int tx = t & 31;
        const int ty = t >> 5;
        #pragma unroll
        for (int i = 0; i < 4; ++i)
            tile[ty + 8 * i][tx] = in[(size_t)(k0 + ty + 8 * i) * N + n0 + tx];
        __syncthreads();
        #pragma unroll
        for (int i = 0; i < 4; ++i)
            outb[(size_t)(n0 + ty + 8 * i) * ostride + k0 + tx] = (short)f2bf(tile[tx][ty + 8 * i]);
        return;
    }
    // degree (spread over M counters — never fold bsum here: R10 lesson)
    const int e = (b - cB - 192) * 256 + t;
    if (e < E) atomicAdd(&deg[dst[e]], 1);
}

// ---------------- CSR build ----------------
__global__ __launch_bounds__(256) void block_sum_kernel(
    const int* __restrict__ deg, int* __restrict__ bsum, int M)
{
    const int b = blockIdx.x, t = threadIdx.x;
    const int idx = b * 1024 + t * 4;
    int s = 0;
    if (idx + 3 < M) {
        const int4 v = *(const int4*)(deg + idx);
        s = v.x + v.y + v.z + v.w;
    } else {
        #pragma unroll
        for (int i = 0; i < 4; ++i) if (idx + i < M) s += deg[idx + i];
    }
    #pragma unroll
    for (int off = 32; off > 0; off >>= 1) s += __shfl_down(s, off);
    __shared__ int ws[4];
    if ((t & 63) == 0) ws[t >> 6] = s;
    __syncthreads();
    if (t == 0) bsum[b] = ws[0] + ws[1] + ws[2] + ws[3];
}

__global__ __launch_bounds__(256) void scan_blocks2_kernel(
    const int* __restrict__ deg, const int* __restrict__ bsum,
    int* __restrict__ rowptr, int* __restrict__ cur, int M, int E, int nB)
{
    const int b = blockIdx.x, t = threadIdx.x;
    __shared__ int sboff;
    if (t < 64) {
        const int v = (t < nB) ? bsum[t] : 0;
        int inc = v;
        #pragma unroll
        for (int off = 1; off < 64; off <<= 1) {
            const int u = __shfl_up(inc, off);
            if (t >= off) inc += u;
        }
        const int prev = __shfl(inc, (b == 0) ? 0 : (b - 1));
        if (t == 0) sboff = (b == 0) ? 0 : prev;
    }
    const int idx = b * 1024 + t * 4;
    int4 d = make_int4(0, 0, 0, 0);
    if (idx + 3 < M) {
        d = *(const int4*)(deg + idx);
    } else {
        if (idx + 0 < M) d.x = deg[idx + 0];
        if (idx + 1 < M) d.y = deg[idx + 1];
        if (idx + 2 < M) d.z = deg[idx + 2];
        if (idx + 3 < M) d.w = deg[idx + 3];
    }
    const int tot = d.x + d.y + d.z + d.w;
    const int lane = t & 63, wid = t >> 6;
    int inc = tot;
    #pragma unroll
    for (int off = 1; off < 64; off <<= 1) {
        const int u = __shfl_up(inc, off);
        if (lane >= off) inc += u;
    }
    __shared__ int wsum[4];
    if (lane == 63) wsum[wid] = inc;
    __syncthreads();
    int woff = 0;
    #pragma unroll
    for (int w = 0; w < 4; ++w) if (w < wid) woff += wsum[w];
    int p = sboff + woff + (inc - tot);
    if (idx + 0 < M) { rowptr[idx + 0] = p; cur[idx + 0] = p; } p += d.x;
    if (idx + 1 < M) { rowptr[idx + 1] = p; cur[idx + 1] = p; } p += d.y;
    if (idx + 2 < M) { rowptr[idx + 2] = p; cur[idx + 2] = p; } p += d.z;
    if (idx + 3 < M) { rowptr[idx + 3] = p; cur[idx + 3] = p; }
    if (b == 0 && t == 0) rowptr[M] = E;
}

__global__ __launch_bounds__(256) void fill_kernel(
    const int* __restrict__ src, const int* __restrict__ dst,
    int* __restrict__ cur, int* __restrict__ srcs, int E)
{
    const int e = blockIdx.x * 256 + threadIdx.x;
    if (e >= E) return;
    const int p = atomicAdd(&cur[dst[e]], 1);
    srcs[p] = src[e];
}

// ---------------- gather d128 from u8 mirror (8 lanes/row x 16B, clamp-predicated) ----------------
__global__ __launch_bounds__(256) void gather_add_d128q(
    const unsigned char* __restrict__ x_q,   // M x 128 u8 (offset-encoded)
    const float* __restrict__ xscale,        // M
    const int* __restrict__ rowptr, const int* __restrict__ srcs,
    short* __restrict__ outb, int M)         // M x S1 bf16
{
    const int row = blockIdx.x * 4 + (threadIdx.x >> 6);
    if (row >= M) return;
    const int lane = threadIdx.x & 63;
    const int g = lane >> 3;           // 8 groups of 8 lanes
    const int o = (lane & 7) * 16;     // 16 u8 elems per lane
    float a[16];
    #pragma unroll
    for (int k = 0; k < 16; ++k) a[k] = 0.f;
    float ssum = 0.f;
    if (g == 0) {                      // self term
        const uint4 u = *(const uint4*)(x_q + (size_t)row * 128 + o);
        const float sc = xscale[row];
        acc16(a, u, sc);
        ssum += sc;
    }
    const int jb = rowptr[row], je = rowptr[row + 1];
    // clamp-predicated: 16 slots/iter, 2 uint4 loads in flight per lane
    for (int j = jb; j < je; j += 16) {
        int ss[2];
        #pragma unroll
        for (int t = 0; t < 2; ++t)
            ss[t] = srcs[min(j + 8 * t + g, je - 1)];
        uint4 v[2]; float sc[2];
        #pragma unroll
        for (int t = 0; t < 2; ++t) {
            v[t] = *(const uint4*)(x_q + (size_t)ss[t] * 128 + o);
            const float scv = xscale[ss[t]];
            sc[t] = (j + 8 * t + g < je) ? scv : 0.f;
        }
        #pragma unroll
        for (int t = 0; t < 2; ++t) { acc16(a, v[t], sc[t]); ssum += sc[t]; }
    }
    // offset correction: dequant = sc*u - 128*sc (per-lane partial, sums to total)
    #pragma unroll
    for (int k = 0; k < 16; ++k) a[k] = fmaf(-128.f, ssum, a[k]);
    // merge the 8 groups (stride-8 tree)
    #pragma unroll
    for (int k = 0; k < 16; ++k) {
        a[k] += __shfl_down(a[k], 8);
        a[k] += __shfl_down(a[k], 16);
        a[k] += __shfl_down(a[k], 32);
    }
    if (g == 0) {                      // lanes 0..7 hold 16 elems each
        uint4 u0, u1;
        u0.x = (unsigned int)f2bf(a[0])  | ((unsigned int)f2bf(a[1])  << 16);
        u0.y = (unsigned int)f2bf(a[2])  | ((unsigned int)f2bf(a[3])  << 16);
        u0.z = (unsigned int)f2bf(a[4])  | ((unsigned int)f2bf(a[5])  << 16);
        u0.w = (unsigned int)f2bf(a[6])  | ((unsigned int)f2bf(a[7])  << 16);
        u1.x = (unsigned int)f2bf(a[8])  | ((unsigned int)f2bf(a[9])  << 16);
        u1.y = (unsigned int)f2bf(a[10]) | ((unsigned int)f2bf(a[11]) << 16);
        u1.z = (unsigned int)f2bf(a[12]) | ((unsigned int)f2bf(a[13]) << 16);
        u1.w = (unsigned int)f2bf(a[14]) | ((unsigned int)f2bf(a[15]) << 16);
        *(uint4*)(outb + (size_t)row * S1 + o)     = u0;
        *(uint4*)(outb + (size_t)row * S1 + o + 8) = u1;
    }
}

// ---------------- gather d256 from uint8 mirror (16 lanes/row x 16B, clamp-predicated) ----------------
__global__ __launch_bounds__(256) void gather_add_d256q(
    const unsigned char* __restrict__ h1q,   // M x 256 uint8 (>=0, no offset)
    const float* __restrict__ hscale,        // M
    const int* __restrict__ rowptr, const int* __restrict__ srcs,
    short* __restrict__ outb, int M)         // M x S2 bf16
{
    const int row = blockIdx.x * 4 + (threadIdx.x >> 6);
    if (row >= M) return;
    const int lane = threadIdx.x & 63;
    const int qt = lane >> 4;          // 4 groups of 16 lanes
    const int o = (lane & 15) * 16;    // 16 u8 elems per lane
    float a[16];
    #pragma unroll
    for (int k = 0; k < 16; ++k) a[k] = 0.f;
    if (qt == 0) {                     // self term (h1q >= 0, no offset)
        const uint4 u = *(const uint4*)(h1q + (size_t)row * 256 + o);
        acc16(a, u, hscale[row]);
    }
    const int jb = rowptr[row], je = rowptr[row + 1];
    // clamp-predicated: 16 slots/iter, 4 uint4 loads in flight per lane
    for (int j = jb; j < je; j += 16) {
        int ss[4];
        #pragma unroll
        for (int t = 0; t < 4; ++t)
            ss[t] = srcs[min(j + 4 * t + qt, je - 1)];
        uint4 v[4]; float sc[4];
        #pragma unroll
        for (int t = 0; t < 4; ++t) {
            v[t] = *(const uint4*)(h1q + (size_t)ss[t] * 256 + o);
            const float scv = hscale[ss[t]];
            sc[t] = (j + 4 * t + qt < je) ? scv : 0.f;
        }
        #pragma unroll
        for (int t = 0; t < 4; ++t) acc16(a, v[t], sc[t]);
    }
    // merge the 4 groups (stride-16 tree)
    #pragma unroll
    for (int k = 0; k < 16; ++k) {
        a[k] += __shfl_down(a[k], 16);
        a[k] += __shfl_down(a[k], 32);
    }
    if (qt == 0) {                     // lanes 0..15 hold 16 elems each
        uint4 u0, u1;
        u0.x = (unsigned int)f2bf(a[0])  | ((unsigned int)f2bf(a[1])  << 16);
        u0.y = (unsigned int)f2bf(a[2])  | ((unsigned int)f2bf(a[3])  << 16);
        u0.z = (unsigned int)f2bf(a[4])  | ((unsigned int)f2bf(a[5])  << 16);
        u0.w = (unsigned int)f2bf(a[6])  | ((unsigned int)f2bf(a[7])  << 16);
        u1.x = (unsigned int)f2bf(a[8])  | ((unsigned int)f2bf(a[9])  << 16);
        u1.y = (unsigned int)f2bf(a[10]) | ((unsigned int)f2bf(a[11]) << 16);
        u1.z = (unsigned int)f2bf(a[12]) | ((unsigned int)f2bf(a[13]) << 16);
        u1.w = (unsigned int)f2bf(a[14]) | ((unsigned int)f2bf(a[15]) << 16);
        *(uint4*)(outb + (size_t)row * S2 + o)     = u0;
        *(uint4*)(outb + (size_t)row * S2 + o + 8) = u1;
    }
}

// ---------------- layer1: h1q = quant(relu(relu(h1in@w1+b1)@w2+b2)) ----------------
__global__ __launch_bounds__(256) void layer1_fused(
    const short* __restrict__ h1in,   // M x S1 (payload 128)
    const short* __restrict__ w1t,    // 256 x S1
    const float* __restrict__ b1,
    const short* __restrict__ w2t,    // 256 x S2
    const float* __restrict__ b2,
    unsigned char* __restrict__ h1q,  // M x 256 uint8
    float* __restrict__ hscale,       // M
    int M)
{
    __shared__ short sT[64 * S2];
    __shared__ float sMax[64][4];
    __shared__ float sInv[64];
    const int tid  = threadIdx.x;
    const int lane = tid & 63;
    const int wid  = tid >> 6;
    const int r16  = lane & 15;
    const int q    = lane >> 4;
    const int tm   = blockIdx.x * 64;
    const int wn   = wid * 64;

    // ---- stage A: async global->LDS, 16B/lane. 64*S1*2 = 17408 B = 1088 chunks.
    {
        const short* Aslice = h1in + (size_t)tm * S1;
        #pragma unroll
        for (int c = 0; c < 4; ++c) {
            const int chunk = c * 256 + tid;            // per-lane global chunk
            GLOAD_LDS16(Aslice + chunk * 8, &sT[(c * 256 + wid * 64) * 8]);
        }
        if (wid == 0)                                    // chunks 1024..1087
            GLOAD_LDS16(Aslice + (1024 + lane) * 8, &sT[1024 * 8]);
    }
    __syncthreads();

    f32x4 acc[4][4];
    #pragma unroll
    for (int i = 0; i < 4; ++i)
        #pragma unroll
        for (int j = 0; j < 4; ++j)
            acc[i][j] = (f32x4)0.f;

    // ---- GEMM1: K=128, A from LDS ----
    #pragma unroll
    for (int k0 = 0; k0 < 128; k0 += 32) {
        bf16x8 af[4], bfr[4];
        #pragma unroll
        for (int i = 0; i < 4; ++i)
            af[i] = *(const bf16x8*)(&sT[(i * 16 + r16) * S1 + k0 + q * 8]);
        #pragma unroll
        for (int j = 0; j < 4; ++j)
            bfr[j] = *(const bf16x8*)(w1t + (size_t)(wn + j * 16 + r16) * S1 + k0 + q * 8);
        #pragma unroll
        for (int i = 0; i < 4; ++i)
            #pragma unroll
            for (int j = 0; j < 4; ++j)
                acc[i][j] = __builtin_amdgcn_mfma_f32_16x16x32_bf16(af[i], bfr[j], acc[i][j], 0, 0, 0);
    }
    __syncthreads();

    // epilogue1 -> sT (S2 layout)
    #pragma unroll
    for (int j = 0; j < 4; ++j) {
        const int col = wn + j * 16 + r16;
        const float bj = b1[col];
        #pragma unroll
        for (int i = 0; i < 4; ++i)
            #pragma unroll
            for (int r = 0; r < 4; ++r) {
                float v = fmaxf(acc[i][j][r] + bj, 0.f);
                sT[(i * 16 + q * 4 + r) * S2 + col] = (short)f2bf(v);
            }
    }
    __syncthreads();

    // ---- GEMM2: K=256, A from sT ----
    #pragma unroll
    for (int i = 0; i < 4; ++i)
        #pragma unroll
        for (int j = 0; j < 4; ++j)
            acc[i][j] = (f32x4)0.f;

    #pragma unroll
    for (int k0 = 0; k0 < 256; k0 += 32) {
        bf16x8 af[4], bfr[4];
        #pragma unroll
        for (int i = 0; i < 4; ++i)
            af[i] = *(const bf16x8*)(&sT[(i * 16 + r16) * S2 + k0 + q * 8]);
        #pragma unroll
        for (int j = 0; j < 4; ++j)
            bfr[j] = *(const bf16x8*)(w2t + (size_t)(wn + j * 16 + r16) * S2 + k0 + q * 8);
        #pragma unroll
        for (int i = 0; i < 4; ++i)
            #pragma unroll
            for (int j = 0; j < 4; ++j)
                acc[i][j] = __builtin_amdgcn_mfma_f32_16x16x32_bf16(af[i], bfr[j], acc[i][j], 0, 0, 0);
    }
    __syncthreads();

    // epilogue2 -> sT + per-row max (this wave's 64-col slice)
    {
        float bj4[4];
        #pragma unroll
        for (int j = 0; j < 4; ++j) bj4[j] = b2[wn + j * 16 + r16];
        #pragma unroll
        for (int i = 0; i < 4; ++i) {
            #pragma unroll
            for (int r = 0; r < 4; ++r) {
                float m = 0.f;
                #pragma unroll
                for (int j = 0; j < 4; ++j) {
                    float v = fmaxf(acc[i][j][r] + bj4[j], 0.f);
                    sT[(i * 16 + q * 4 + r) * S2 + wn + j * 16 + r16] = (short)f2bf(v);
                    m = fmaxf(m, v);
                }
                #pragma unroll
                for (int off = 1; off < 16; off <<= 1)
                    m = fmaxf(m, __shfl_xor(m, off));
                if (r16 == 0) sMax[i * 16 + q * 4 + r][wid] = m;
            }
        }
    }
    __syncthreads();

    if (tid < 64) {
        const float m = fmaxf(fmaxf(sMax[tid][0], sMax[tid][1]),
                              fmaxf(sMax[tid][2], sMax[tid][3]));
        sInv[tid] = (m > 0.f) ? 255.f / m : 0.f;
        const int rg = tm + tid;
        if (rg < M) hscale[rg] = m * (1.f / 255.f);
    }
    __syncthreads();

    // quantized store: 64 rows x 256 uint8
    #pragma unroll
    for (int c = 0; c < 8; ++c) {
        const int idx = tid + c * 256;
        const int row = idx >> 5;
        const int ch  = idx & 31;
        const int rg  = tm + row;
        if (rg < M) {
            const uint4 v = *(const uint4*)(&sT[row * S2 + ch * 8]);
            const float inv = sInv[row];
            unsigned int q0 = min(255u, (unsigned int)(bflo(v.x) * inv + 0.5f));
            unsigned int q1 = min(255u, (unsigned int)(bfhi(v.x) * inv + 0.5f));
            unsigned int q2 = min(255u, (unsigned int)(bflo(v.y) * inv + 0.5f));
            unsigned int q3 = min(255u, (unsigned int)(bfhi(v.y) * inv + 0.5f));
            unsigned int q4 = min(255u, (unsigned int)(bflo(v.z) * inv + 0.5f));
            unsigned int q5 = min(255u, (unsigned int)(bfhi(v.z) * inv + 0.5f));
            unsigned int q6 = min(255u, (unsigned int)(bflo(v.w) * inv + 0.5f));
            unsigned int q7 = min(255u, (unsigned int)(bfhi(v.w) * inv + 0.5f));
            uint2 o8;
            o8.x = q0 | (q1 << 8) | (q2 << 16) | (q3 << 24);
            o8.y = q4 | (q5 << 8) | (q6 << 16) | (q7 << 24);
            *(uint2*)(h1q + (size_t)rg * 256 + ch * 8) = o8;
        }
    }
}

// ---------------- layer2: out = log_softmax(relu(h2in@w3+b3) @ w4 + b4) ----------------
__global__ __launch_bounds__(256) void layer2_fused(
    const short* __restrict__ h2in,   // M x S2 (payload 256)
    const short* __restrict__ w3t,    // 256 x S2
    const float* __restrict__ b3,
    const float* __restrict__ w4,     // 256 x 2 fp32
    const float* __restrict__ b4,
    float* __restrict__ out,          // M x 2
    int M)
{
    __shared__ short sT[64 * S2];
    const int tid  = threadIdx.x;
    const int lane = tid & 63;
    const int wid  = tid >> 6;
    const int r16  = lane & 15;
    const int q    = lane >> 4;
    const int tm   = blockIdx.x * 64;
    const int wn   = wid * 64;

    // ---- stage A: async global->LDS, 16B/lane. 64*S2*2 = 33792 B = 2112 chunks.
    {
        const short* Aslice = h2in + (size_t)tm * S2;
        #pragma unroll
        for (int c = 0; c < 8; ++c) {
            const int chunk = c * 256 + tid;
            GLOAD_LDS16(Aslice + chunk * 8, &sT[(c * 256 + wid * 64) * 8]);
        }
        if (wid == 0)                                    // chunks 2048..2111
            GLOAD_LDS16(Aslice + (2048 + lane) * 8, &sT[2048 * 8]);
    }
    __syncthreads();

    f32x4 acc[4][4];
    #pragma unroll
    for (int i = 0; i < 4; ++i)
        #pragma unroll
        for (int j = 0; j < 4; ++j)
            acc[i][j] = (f32x4)0.f;

    #pragma unroll
    for (int k0 = 0; k0 < 256; k0 += 32) {
        bf16x8 af[4], bfr[4];
        #pragma unroll
        for (int i = 0; i < 4; ++i)
            af[i] = *(const bf16x8*)(&sT[(i * 16 + r16) * S2 + k0 + q * 8]);
        #pragma unroll
        for (int j = 0; j < 4; ++j)
            bfr[j] = *(const bf16x8*)(w3t + (size_t)(wn + j * 16 + r16) * S2 + k0 + q * 8);
        #pragma unroll
        for (int i = 0; i < 4; ++i)
            #pragma unroll
            for (int j = 0; j < 4; ++j)
                acc[i][j] = __builtin_amdgcn_mfma_f32_16x16x32_bf16(af[i], bfr[j], acc[i][j], 0, 0, 0);
    }
    __syncthreads();

    #pragma unroll
    for (int j = 0; j < 4; ++j) {
        const int col = wn + j * 16 + r16;
        const float bj = b3[col];
        #pragma unroll
        for (int i = 0; i < 4; ++i)
            #pragma unroll
            for (int r = 0; r < 4; ++r) {
                float v = fmaxf(acc[i][j][r] + bj, 0.f);
                sT[(i * 16 + q * 4 + r) * S2 + col] = (short)f2bf(v);
            }
    }
    __syncthreads();

    // w4-dot tail: 8x ds_read_b128 per thread, identical summation order
    const int row = tid >> 2;
    const int qd  = tid & 3;
    const short* tp = &sT[row * S2 + qd * 64];
    const float* w4p = w4 + qd * 128;
    float s0 = 0.f, s1 = 0.f;
    #pragma unroll
    for (int c8 = 0; c8 < 8; ++c8) {
        const uint4 v = *(const uint4*)(tp + c8 * 8);
        float av[8];
        av[0] = bflo(v.x); av[1] = bfhi(v.x);
        av[2] = bflo(v.y); av[3] = bfhi(v.y);
        av[4] = bflo(v.z); av[5] = bfhi(v.z);
        av[6] = bflo(v.w); av[7] = bfhi(v.w);
        const float2* wp = (const float2*)(w4p + c8 * 16);
        #pragma unroll
        for (int k = 0; k < 8; ++k) {
            const float2 w = wp[k];
            s0 = fmaf(av[k], w.x, s0);
            s1 = fmaf(av[k], w.y, s1);
        }
    }
    s0 += __shfl_down(s0, 2, 4);  s1 += __shfl_down(s1, 2, 4);
    s0 += __shfl_down(s0, 1, 4);  s1 += __shfl_down(s1, 1, 4);
    if (qd == 0) {
        const int rg = tm + row;
        if (rg < M) {
            s0 += b4[0];
            s1 += b4[1];
            const float m = fmaxf(s0, s1);
            const float l = logf(__expf(s0 - m) + __expf(s1 - m));
            float2 o;
            o.x = s0 - m - l;
            o.y = s1 - m - l;
            *(float2*)(out + (size_t)rg * 2) = o;
        }
    }
}

extern "C" void kernel_launch(void* const* d_in, const int* in_sizes, int n_in,
                              void* d_out, int out_size, void* d_ws, size_t ws_size,
                              hipStream_t stream)
{
    const float* x  = (const float*)d_in[0];
    const int*   ei = (const int*)d_in[1];
    const float* w1 = (const float*)d_in[2];
    const float* b1 = (const float*)d_in[3];
    const float* w2 = (const float*)d_in[4];
    const float* b2 = (const float*)d_in[5];
    const float* w3 = (const float*)d_in[6];
    const float* b3 = (const float*)d_in[7];
    const float* w4 = (const float*)d_in[8];
    const float* b4 = (const float*)d_in[9];

    const int DIN = 128, DH = 256;
    const int M = in_sizes[0] / DIN;   // 50000
    const int E = in_sizes[1] / 2;     // 600000
    const int* src = ei;
    const int* dst = ei + E;
    const int nB = (M + 1023) / 1024;  // <= 64

    // -------- workspace layout --------
    int* deg    = (int*)d_ws;          // M
    int* bsum   = deg + M;             // 64
    int* cur    = bsum + 64;           // M
    int* rowptr = cur + M;             // M+1
    int* srcs   = rowptr + (M + 1);    // E
    size_t off = ((size_t)(3 * M + 1 + 64 + E) * sizeof(int) + 255) & ~(size_t)255;
    unsigned char* x_q = (unsigned char*)((char*)d_ws + off);  off += (size_t)M * 128;  // M x 128 u8
    off = (off + 255) & ~(size_t)255;
    float* xscale = (float*)((char*)d_ws + off);  off += (size_t)M * 4;
    off = (off + 255) & ~(size_t)255;
    short* h1in = (short*)((char*)d_ws + off);  off += (size_t)M * S1 * 2;    // M x 136 bf16
    off = (off + 255) & ~(size_t)255;
    unsigned char* h1q = (unsigned char*)((char*)d_ws + off);  off += (size_t)M * 256; // M x 256 u8
    off = (off + 255) & ~(size_t)255;
    float* hscale = (float*)((char*)d_ws + off);  off += (size_t)M * 4;
    off = (off + 255) & ~(size_t)255;
    short* h2in = (short*)((char*)d_ws + off);  off += (size_t)M * S2 * 2;    // M x 264 bf16
    off = (off + 255) & ~(size_t)255;
    short* w1t  = (short*)((char*)d_ws + off);  off += (size_t)DH * S1 * 2;
    off = (off + 255) & ~(size_t)255;
    short* w2t  = (short*)((char*)d_ws + off);  off += (size_t)DH * S2 * 2;
    off = (off + 255) & ~(size_t)255;
    short* w3t  = (short*)((char*)d_ws + off);  off += (size_t)DH * S2 * 2;

    // -------- prep --------
    hipMemsetAsync(deg, 0, (size_t)M * sizeof(int), stream);
    const int cB = (M * 32 + 255) / 256;
    const int dB = (E + 255) / 256;
    prep_kernel<<<cB + 192 + dB, 256, 0, stream>>>(
        x, x_q, xscale, w1, w2, w3, w1t, w2t, w3t, dst, deg, M, E, cB);

    // -------- CSR build --------
    block_sum_kernel<<<nB, 256, 0, stream>>>(deg, bsum, M);
    scan_blocks2_kernel<<<nB, 256, 0, stream>>>(deg, bsum, rowptr, cur, M, E, nB);
    fill_kernel<<<dB, 256, 0, stream>>>(src, dst, cur, srcs, E);

    const int nblk = (M + 63) / 64;

    // -------- layer 1 --------
    gather_add_d128q<<<(M + 3) / 4, 256, 0, stream>>>(x_q, xscale, rowptr, srcs, h1in, M);
    layer1_fused<<<nblk, 256, 0, stream>>>(h1in, w1t, b1, w2t, b2, h1q, hscale, M);

    // -------- layer 2 --------
    gather_add_d256q<<<(M + 3) / 4, 256, 0, stream>>>(h1q, hscale, rowptr, srcs, h2in, M);
    layer2_fused<<<nblk, 256, 0, stream>>>(h2in, w3t, b3, w4, b4, (float*)d_out, M);
}

// Round 6
// 265.002 us; speedup vs baseline: 1.0829x; 1.0829x over previous
//
#include <hip/hip_runtime.h>
#include <hip/hip_bf16.h>

// GIN 2-layer forward — R20: R18 (best, 266.6µs) + fragment-major weight
// layout. R19 (16B/lane gathers) REGRESSED (287µs, d256 gather 45µs, worse
// L2 reuse) — gathers reverted to R18's uint2 shape. New lever: the layer
// GEMMs' B-fragment loads read 16 rows strided by S2*2=528B per wave instr
// (~64 cache lines). Weights are now stored fragment-major:
//   wt[cb][kb][r16*32 + q*8 + e], cb=col/16, kb=k/32
// so each wave fragment-load is 64 lanes x 16B contiguous (4 lines).
// Bit-identical numerics (same values, same lanes, same order).
//
//   memset(deg) -> prep (quant x -> u8 + scale | transpose w | degree atomics)
//   block_sum -> scan_blocks2 -> fill
//   h1in  = dequant-gather(x_q)                        [bf16, stride 136]
//   h1q,hscale = quant(relu(relu(h1in@w1+b1)@w2+b2))   [layer1_fused, uint8 out]
//   h2in  = dequant-gather(h1q)                        [bf16, stride 264]
//   out   = log_softmax(relu(h2in@w3+b3)@w4+b4)        [layer2_fused]

typedef __attribute__((ext_vector_type(8))) short bf16x8;
typedef __attribute__((ext_vector_type(4))) float f32x4;

#define GLOAD_LDS16(g, l)                                                     \
    __builtin_amdgcn_global_load_lds(                                         \
        (const __attribute__((address_space(1))) void*)(g),                   \
        (__attribute__((address_space(3))) void*)(l), 16, 0, 0)

static __device__ __forceinline__ unsigned short f2bf(float f) {
    unsigned int u = __float_as_uint(f);
    unsigned int r = (u + 0x7fffu + ((u >> 16) & 1u)) >> 16;
    return (unsigned short)r;
}
static __device__ __forceinline__ float bf2f(unsigned short s) {
    return __uint_as_float(((unsigned int)s) << 16);
}
static __device__ __forceinline__ float bflo(unsigned int u) {
    return __uint_as_float(u << 16);
}
static __device__ __forceinline__ float bfhi(unsigned int u) {
    return __uint_as_float(u & 0xffff0000u);
}

#define S1 136   // 128 + 8 pad (bf16 elems)
#define S2 264   // 256 + 8 pad

// accumulate 8 uint8 lanes (packed uint2) scaled by ss into a[0..7]
// (ubyte extracts fold to v_cvt_f32_ubyte0..3)
static __device__ __forceinline__ void acc8(float* a, uint2 v, float ss) {
    a[0] = fmaf(ss, (float)( v.x        & 0xff), a[0]);
    a[1] = fmaf(ss, (float)((v.x >> 8 ) & 0xff), a[1]);
    a[2] = fmaf(ss, (float)((v.x >> 16) & 0xff), a[2]);
    a[3] = fmaf(ss, (float)( v.x >> 24        ), a[3]);
    a[4] = fmaf(ss, (float)( v.y        & 0xff), a[4]);
    a[5] = fmaf(ss, (float)((v.y >> 8 ) & 0xff), a[5]);
    a[6] = fmaf(ss, (float)((v.y >> 16) & 0xff), a[6]);
    a[7] = fmaf(ss, (float)( v.y >> 24        ), a[7]);
}

// ---------------- prep: quant x | transpose w1/w2/w3 (fragment-major) | degree ----------------
__global__ __launch_bounds__(256) void prep_kernel(
    const float* __restrict__ x,
    unsigned char* __restrict__ x_q, float* __restrict__ xscale,
    const float* __restrict__ w1, const float* __restrict__ w2, const float* __restrict__ w3,
    short* __restrict__ w1t, short* __restrict__ w2t, short* __restrict__ w3t,
    const int* __restrict__ dst, int* __restrict__ deg,
    int M, int E, int cB)
{
    const int b = blockIdx.x;
    const int t = threadIdx.x;
    if (b < cB) {
        // quantize x -> offset u8, per-row (128 elems = 32 threads) absmax scale
        const int i = b * 256 + t;       // global 4-elem group
        const int n4 = M * 32;           // M*128/4
        if (i >= n4) return;
        const float4 v = *(const float4*)(x + (size_t)i * 4);
        float mx = fmaxf(fmaxf(fabsf(v.x), fabsf(v.y)), fmaxf(fabsf(v.z), fabsf(v.w)));
        #pragma unroll
        for (int o2 = 1; o2 < 32; o2 <<= 1)
            mx = fmaxf(mx, __shfl_xor(mx, o2));      // butterfly within 32-lane row group
        const float inv = (mx > 0.f) ? 127.f / mx : 0.f;
        uchar4 o;
        o.x = (unsigned char)(int)(v.x * inv + 128.5f);
        o.y = (unsigned char)(int)(v.y * inv + 128.5f);
        o.z = (unsigned char)(int)(v.z * inv + 128.5f);
        o.w = (unsigned char)(int)(v.w * inv + 128.5f);
        const int row = i >> 5;
        *(uchar4*)(x_q + (size_t)row * 128 + (i & 31) * 4) = o;
        if ((t & 31) == 0) xscale[row] = (mx > 0.f) ? mx * (1.f / 127.f) : 0.f;
        return;
    }
    if (b < cB + 192) {
        const int tb = b - cB;
        const int z = tb >> 6;
        const int rem = tb & 63;
        const int kb = rem & 7;
        const int nb = rem >> 3;
        const float* in; short* outb; int K, nKB;
        if (z == 0)      { in = w1; outb = w1t; K = 128; nKB = 4; }
        else if (z == 1) { in = w2; outb = w2t; K = 256; nKB = 8; }
        else             { in = w3; outb = w3t; K = 256; nKB = 8; }
        const int N = 256;
        const int k0 = kb * 32;
        if (k0 >= K) return;
        const int n0 = nb * 32;
        __shared__ float tile[32][33];
        const int tx = t & 31;
        const int ty = t >> 5;
        #pragma unroll
        for (int i = 0; i < 4; ++i)
            tile[ty + 8 * i][tx] = in[(size_t)(k0 + ty + 8 * i) * N + n0 + tx];
        __syncthreads();
        // fragment-major write: wt[((n>>4)*nKB + kb)*512 + (n&15)*32 + (k&31)]
        // n = n0+ty+8i, k = k0+tx  (k>>5 == kb; k&31 == tx)  — contiguous in tx
        #pragma unroll
        for (int i = 0; i < 4; ++i) {
            const int n = n0 + ty + 8 * i;
            outb[(size_t)(((n >> 4) * nKB + kb) << 9) + (n & 15) * 32 + tx]
                = (short)f2bf(tile[tx][ty + 8 * i]);
        }
        return;
    }
    // degree (spread over M counters — never fold bsum here: R10 lesson)
    const int e = (b - cB - 192) * 256 + t;
    if (e < E) atomicAdd(&deg[dst[e]], 1);
}

// ---------------- CSR build ----------------
__global__ __launch_bounds__(256) void block_sum_kernel(
    const int* __restrict__ deg, int* __restrict__ bsum, int M)
{
    const int b = blockIdx.x, t = threadIdx.x;
    const int idx = b * 1024 + t * 4;
    int s = 0;
    if (idx + 3 < M) {
        const int4 v = *(const int4*)(deg + idx);
        s = v.x + v.y + v.z + v.w;
    } else {
        #pragma unroll
        for (int i = 0; i < 4; ++i) if (idx + i < M) s += deg[idx + i];
    }
    #pragma unroll
    for (int off = 32; off > 0; off >>= 1) s += __shfl_down(s, off);
    __shared__ int ws[4];
    if ((t & 63) == 0) ws[t >> 6] = s;
    __syncthreads();
    if (t == 0) bsum[b] = ws[0] + ws[1] + ws[2] + ws[3];
}

__global__ __launch_bounds__(256) void scan_blocks2_kernel(
    const int* __restrict__ deg, const int* __restrict__ bsum,
    int* __restrict__ rowptr, int* __restrict__ cur, int M, int E, int nB)
{
    const int b = blockIdx.x, t = threadIdx.x;
    __shared__ int sboff;
    if (t < 64) {
        const int v = (t < nB) ? bsum[t] : 0;
        int inc = v;
        #pragma unroll
        for (int off = 1; off < 64; off <<= 1) {
            const int u = __shfl_up(inc, off);
            if (t >= off) inc += u;
        }
        const int prev = __shfl(inc, (b == 0) ? 0 : (b - 1));
        if (t == 0) sboff = (b == 0) ? 0 : prev;
    }
    const int idx = b * 1024 + t * 4;
    int4 d = make_int4(0, 0, 0, 0);
    if (idx + 3 < M) {
        d = *(const int4*)(deg + idx);
    } else {
        if (idx + 0 < M) d.x = deg[idx + 0];
        if (idx + 1 < M) d.y = deg[idx + 1];
        if (idx + 2 < M) d.z = deg[idx + 2];
        if (idx + 3 < M) d.w = deg[idx + 3];
    }
    const int tot = d.x + d.y + d.z + d.w;
    const int lane = t & 63, wid = t >> 6;
    int inc = tot;
    #pragma unroll
    for (int off = 1; off < 64; off <<= 1) {
        const int u = __shfl_up(inc, off);
        if (lane >= off) inc += u;
    }
    __shared__ int wsum[4];
    if (lane == 63) wsum[wid] = inc;
    __syncthreads();
    int woff = 0;
    #pragma unroll
    for (int w = 0; w < 4; ++w) if (w < wid) woff += wsum[w];
    int p = sboff + woff + (inc - tot);
    if (idx + 0 < M) { rowptr[idx + 0] = p; cur[idx + 0] = p; } p += d.x;
    if (idx + 1 < M) { rowptr[idx + 1] = p; cur[idx + 1] = p; } p += d.y;
    if (idx + 2 < M) { rowptr[idx + 2] = p; cur[idx + 2] = p; } p += d.z;
    if (idx + 3 < M) { rowptr[idx + 3] = p; cur[idx + 3] = p; }
    if (b == 0 && t == 0) rowptr[M] = E;
}

__global__ __launch_bounds__(256) void fill_kernel(
    const int* __restrict__ src, const int* __restrict__ dst,
    int* __restrict__ cur, int* __restrict__ srcs, int E)
{
    const int e = blockIdx.x * 256 + threadIdx.x;
    if (e >= E) return;
    const int p = atomicAdd(&cur[dst[e]], 1);
    srcs[p] = src[e];
}

// ---------------- gather d128 from u8 mirror (quarter-wave, clamp-predicated) ----------------
__global__ __launch_bounds__(256) void gather_add_d128q(
    const unsigned char* __restrict__ x_q,   // M x 128 u8 (offset-encoded)
    const float* __restrict__ xscale,        // M
    const int* __restrict__ rowptr, const int* __restrict__ srcs,
    short* __restrict__ outb, int M)         // M x S1 bf16
{
    const int row = blockIdx.x * 4 + (threadIdx.x >> 6);
    if (row >= M) return;
    const int lane = threadIdx.x & 63;
    const int qt = lane >> 4;          // quarter 0..3
    const int o = (lane & 15) * 8;     // byte/elem offset (8 elems per lane)
    float a[8];
    #pragma unroll
    for (int k = 0; k < 8; ++k) a[k] = 0.f;
    float ssum = 0.f;
    if (qt == 0) {                     // self term
        const uint2 u = *(const uint2*)(x_q + (size_t)row * 128 + o);
        const float sc = xscale[row];
        acc8(a, u, sc);
        ssum += sc;
    }
    const int jb = rowptr[row], je = rowptr[row + 1];
    // flat clamp-predicated loop: 16 slots/iter, 4 rows in flight per lane.
    for (int j = jb; j < je; j += 16) {
        int ss[4];
        #pragma unroll
        for (int t = 0; t < 4; ++t)
            ss[t] = srcs[min(j + 4 * t + qt, je - 1)];
        uint2 v[4]; float sc[4];
        #pragma unroll
        for (int t = 0; t < 4; ++t) {
            v[t] = *(const uint2*)(x_q + (size_t)ss[t] * 128 + o);
            const float scv = xscale[ss[t]];
            sc[t] = (j + 4 * t + qt < je) ? scv : 0.f;
        }
        #pragma unroll
        for (int t = 0; t < 4; ++t) { acc8(a, v[t], sc[t]); ssum += sc[t]; }
    }
    // offset correction: dequant = sc*u - 128*sc
    #pragma unroll
    for (int k = 0; k < 8; ++k) a[k] = fmaf(-128.f, ssum, a[k]);
    // merge quarters
    #pragma unroll
    for (int k = 0; k < 8; ++k) {
        a[k] += __shfl_down(a[k], 16);
        a[k] += __shfl_down(a[k], 32);
    }
    if (qt == 0) {
        uint4 up;
        up.x = (unsigned int)f2bf(a[0]) | ((unsigned int)f2bf(a[1]) << 16);
        up.y = (unsigned int)f2bf(a[2]) | ((unsigned int)f2bf(a[3]) << 16);
        up.z = (unsigned int)f2bf(a[4]) | ((unsigned int)f2bf(a[5]) << 16);
        up.w = (unsigned int)f2bf(a[6]) | ((unsigned int)f2bf(a[7]) << 16);
        *(uint4*)(outb + (size_t)row * S1 + o) = up;
    }
}

// ---------------- gather d256 from uint8 mirror (half-wave, clamp-predicated) ----------------
__global__ __launch_bounds__(256) void gather_add_d256q(
    const unsigned char* __restrict__ h1q,   // M x 256 uint8 (>=0, no offset)
    const float* __restrict__ hscale,        // M
    const int* __restrict__ rowptr, const int* __restrict__ srcs,
    short* __restrict__ outb, int M)         // M x S2 bf16
{
    const int row = blockIdx.x * 4 + (threadIdx.x >> 6);
    if (row >= M) return;
    const int lane = threadIdx.x & 63;
    const int half = lane >> 5;
    const int o = (lane & 31) * 8;
    float a[8];
    #pragma unroll
    for (int k = 0; k < 8; ++k) a[k] = 0.f;
    if (half == 0) {
        const uint2 u = *(const uint2*)(h1q + (size_t)row * 256 + o);
        acc8(a, u, hscale[row]);
    }
    const int jb = rowptr[row], je = rowptr[row + 1];
    // flat clamp-predicated loop: 16 slots/iter, 8 rows in flight per lane
    for (int j = jb; j < je; j += 16) {
        int ss[8];
        #pragma unroll
        for (int t = 0; t < 8; ++t)
            ss[t] = srcs[min(j + 2 * t + half, je - 1)];
        uint2 v[8]; float sc[8];
        #pragma unroll
        for (int t = 0; t < 8; ++t) {
            v[t] = *(const uint2*)(h1q + (size_t)ss[t] * 256 + o);
            const float scv = hscale[ss[t]];
            sc[t] = (j + 2 * t + half < je) ? scv : 0.f;
        }
        #pragma unroll
        for (int t = 0; t < 8; ++t) acc8(a, v[t], sc[t]);
    }
    #pragma unroll
    for (int k = 0; k < 8; ++k) a[k] += __shfl_down(a[k], 32);
    if (half == 0) {
        uint4 up;
        up.x = (unsigned int)f2bf(a[0]) | ((unsigned int)f2bf(a[1]) << 16);
        up.y = (unsigned int)f2bf(a[2]) | ((unsigned int)f2bf(a[3]) << 16);
        up.z = (unsigned int)f2bf(a[4]) | ((unsigned int)f2bf(a[5]) << 16);
        up.w = (unsigned int)f2bf(a[6]) | ((unsigned int)f2bf(a[7]) << 16);
        *(uint4*)(outb + (size_t)row * S2 + o) = up;
    }
}

// ---------------- layer1: h1q = quant(relu(relu(h1in@w1+b1)@w2+b2)) ----------------
__global__ __launch_bounds__(256) void layer1_fused(
    const short* __restrict__ h1in,   // M x S1 (payload 128)
    const short* __restrict__ w1t,    // fragment-major, nKB=4
    const float* __restrict__ b1,
    const short* __restrict__ w2t,    // fragment-major, nKB=8
    const float* __restrict__ b2,
    unsigned char* __restrict__ h1q,  // M x 256 uint8
    float* __restrict__ hscale,       // M
    int M)
{
    __shared__ short sT[64 * S2];
    __shared__ float sMax[64][4];
    __shared__ float sInv[64];
    const int tid  = threadIdx.x;
    const int lane = tid & 63;
    const int wid  = tid >> 6;
    const int r16  = lane & 15;
    const int q    = lane >> 4;
    const int tm   = blockIdx.x * 64;
    const int wn   = wid * 64;
    const int fo   = r16 * 32 + q * 8;   // fragment-internal offset

    // ---- stage A: async global->LDS, 16B/lane. 64*S1*2 = 17408 B = 1088 chunks.
    {
        const short* Aslice = h1in + (size_t)tm * S1;
        #pragma unroll
        for (int c = 0; c < 4; ++c) {
            const int chunk = c * 256 + tid;            // per-lane global chunk
            GLOAD_LDS16(Aslice + chunk * 8, &sT[(c * 256 + wid * 64) * 8]);
        }
        if (wid == 0)                                    // chunks 1024..1087
            GLOAD_LDS16(Aslice + (1024 + lane) * 8, &sT[1024 * 8]);
    }
    __syncthreads();

    f32x4 acc[4][4];
    #pragma unroll
    for (int i = 0; i < 4; ++i)
        #pragma unroll
        for (int j = 0; j < 4; ++j)
            acc[i][j] = (f32x4)0.f;

    // ---- GEMM1: K=128, A from LDS, B fragment-major (nKB=4) ----
    #pragma unroll
    for (int k0 = 0; k0 < 128; k0 += 32) {
        const int kb = k0 >> 5;
        bf16x8 af[4], bfr[4];
        #pragma unroll
        for (int i = 0; i < 4; ++i)
            af[i] = *(const bf16x8*)(&sT[(i * 16 + r16) * S1 + k0 + q * 8]);
        #pragma unroll
        for (int j = 0; j < 4; ++j)
            bfr[j] = *(const bf16x8*)(w1t + (size_t)(((wid * 4 + j) * 4 + kb) << 9) + fo);
        #pragma unroll
        for (int i = 0; i < 4; ++i)
            #pragma unroll
            for (int j = 0; j < 4; ++j)
                acc[i][j] = __builtin_amdgcn_mfma_f32_16x16x32_bf16(af[i], bfr[j], acc[i][j], 0, 0, 0);
    }
    __syncthreads();

    // epilogue1 -> sT (S2 layout)
    #pragma unroll
    for (int j = 0; j < 4; ++j) {
        const int col = wn + j * 16 + r16;
        const float bj = b1[col];
        #pragma unroll
        for (int i = 0; i < 4; ++i)
            #pragma unroll
            for (int r = 0; r < 4; ++r) {
                float v = fmaxf(acc[i][j][r] + bj, 0.f);
                sT[(i * 16 + q * 4 + r) * S2 + col] = (short)f2bf(v);
            }
    }
    __syncthreads();

    // ---- GEMM2: K=256, A from sT, B fragment-major (nKB=8) ----
    #pragma unroll
    for (int i = 0; i < 4; ++i)
        #pragma unroll
        for (int j = 0; j < 4; ++j)
            acc[i][j] = (f32x4)0.f;

    #pragma unroll
    for (int k0 = 0; k0 < 256; k0 += 32) {
        const int kb = k0 >> 5;
        bf16x8 af[4], bfr[4];
        #pragma unroll
        for (int i = 0; i < 4; ++i)
            af[i] = *(const bf16x8*)(&sT[(i * 16 + r16) * S2 + k0 + q * 8]);
        #pragma unroll
        for (int j = 0; j < 4; ++j)
            bfr[j] = *(const bf16x8*)(w2t + (size_t)(((wid * 4 + j) * 8 + kb) << 9) + fo);
        #pragma unroll
        for (int i = 0; i < 4; ++i)
            #pragma unroll
            for (int j = 0; j < 4; ++j)
                acc[i][j] = __builtin_amdgcn_mfma_f32_16x16x32_bf16(af[i], bfr[j], acc[i][j], 0, 0, 0);
    }
    __syncthreads();

    // epilogue2 -> sT + per-row max (this wave's 64-col slice)
    {
        float bj4[4];
        #pragma unroll
        for (int j = 0; j < 4; ++j) bj4[j] = b2[wn + j * 16 + r16];
        #pragma unroll
        for (int i = 0; i < 4; ++i) {
            #pragma unroll
            for (int r = 0; r < 4; ++r) {
                float m = 0.f;
                #pragma unroll
                for (int j = 0; j < 4; ++j) {
                    float v = fmaxf(acc[i][j][r] + bj4[j], 0.f);
                    sT[(i * 16 + q * 4 + r) * S2 + wn + j * 16 + r16] = (short)f2bf(v);
                    m = fmaxf(m, v);
                }
                #pragma unroll
                for (int off = 1; off < 16; off <<= 1)
                    m = fmaxf(m, __shfl_xor(m, off));
                if (r16 == 0) sMax[i * 16 + q * 4 + r][wid] = m;
            }
        }
    }
    __syncthreads();

    if (tid < 64) {
        const float m = fmaxf(fmaxf(sMax[tid][0], sMax[tid][1]),
                              fmaxf(sMax[tid][2], sMax[tid][3]));
        sInv[tid] = (m > 0.f) ? 255.f / m : 0.f;
        const int rg = tm + tid;
        if (rg < M) hscale[rg] = m * (1.f / 255.f);
    }
    __syncthreads();

    // quantized store: 64 rows x 256 uint8
    #pragma unroll
    for (int c = 0; c < 8; ++c) {
        const int idx = tid + c * 256;
        const int row = idx >> 5;
        const int ch  = idx & 31;
        const int rg  = tm + row;
        if (rg < M) {
            const uint4 v = *(const uint4*)(&sT[row * S2 + ch * 8]);
            const float inv = sInv[row];
            unsigned int q0 = min(255u, (unsigned int)(bflo(v.x) * inv + 0.5f));
            unsigned int q1 = min(255u, (unsigned int)(bfhi(v.x) * inv + 0.5f));
            unsigned int q2 = min(255u, (unsigned int)(bflo(v.y) * inv + 0.5f));
            unsigned int q3 = min(255u, (unsigned int)(bfhi(v.y) * inv + 0.5f));
            unsigned int q4 = min(255u, (unsigned int)(bflo(v.z) * inv + 0.5f));
            unsigned int q5 = min(255u, (unsigned int)(bfhi(v.z) * inv + 0.5f));
            unsigned int q6 = min(255u, (unsigned int)(bflo(v.w) * inv + 0.5f));
            unsigned int q7 = min(255u, (unsigned int)(bfhi(v.w) * inv + 0.5f));
            uint2 o8;
            o8.x = q0 | (q1 << 8) | (q2 << 16) | (q3 << 24);
            o8.y = q4 | (q5 << 8) | (q6 << 16) | (q7 << 24);
            *(uint2*)(h1q + (size_t)rg * 256 + ch * 8) = o8;
        }
    }
}

// ---------------- layer2: out = log_softmax(relu(h2in@w3+b3) @ w4 + b4) ----------------
__global__ __launch_bounds__(256) void layer2_fused(
    const short* __restrict__ h2in,   // M x S2 (payload 256)
    const short* __restrict__ w3t,    // fragment-major, nKB=8
    const float* __restrict__ b3,
    const float* __restrict__ w4,     // 256 x 2 fp32
    const float* __restrict__ b4,
    float* __restrict__ out,          // M x 2
    int M)
{
    __shared__ short sT[64 * S2];
    const int tid  = threadIdx.x;
    const int lane = tid & 63;
    const int wid  = tid >> 6;
    const int r16  = lane & 15;
    const int q    = lane >> 4;
    const int tm   = blockIdx.x * 64;
    const int wn   = wid * 64;
    const int fo   = r16 * 32 + q * 8;

    // ---- stage A: async global->LDS, 16B/lane. 64*S2*2 = 33792 B = 2112 chunks.
    {
        const short* Aslice = h2in + (size_t)tm * S2;
        #pragma unroll
        for (int c = 0; c < 8; ++c) {
            const int chunk = c * 256 + tid;
            GLOAD_LDS16(Aslice + chunk * 8, &sT[(c * 256 + wid * 64) * 8]);
        }
        if (wid == 0)                                    // chunks 2048..2111
            GLOAD_LDS16(Aslice + (2048 + lane) * 8, &sT[2048 * 8]);
    }
    __syncthreads();

    f32x4 acc[4][4];
    #pragma unroll
    for (int i = 0; i < 4; ++i)
        #pragma unroll
        for (int j = 0; j < 4; ++j)
            acc[i][j] = (f32x4)0.f;

    #pragma unroll
    for (int k0 = 0; k0 < 256; k0 += 32) {
        const int kb = k0 >> 5;
        bf16x8 af[4], bfr[4];
        #pragma unroll
        for (int i = 0; i < 4; ++i)
            af[i] = *(const bf16x8*)(&sT[(i * 16 + r16) * S2 + k0 + q * 8]);
        #pragma unroll
        for (int j = 0; j < 4; ++j)
            bfr[j] = *(const bf16x8*)(w3t + (size_t)(((wid * 4 + j) * 8 + kb) << 9) + fo);
        #pragma unroll
        for (int i = 0; i < 4; ++i)
            #pragma unroll
            for (int j = 0; j < 4; ++j)
                acc[i][j] = __builtin_amdgcn_mfma_f32_16x16x32_bf16(af[i], bfr[j], acc[i][j], 0, 0, 0);
    }
    __syncthreads();

    #pragma unroll
    for (int j = 0; j < 4; ++j) {
        const int col = wn + j * 16 + r16;
        const float bj = b3[col];
        #pragma unroll
        for (int i = 0; i < 4; ++i)
            #pragma unroll
            for (int r = 0; r < 4; ++r) {
                float v = fmaxf(acc[i][j][r] + bj, 0.f);
                sT[(i * 16 + q * 4 + r) * S2 + col] = (short)f2bf(v);
            }
    }
    __syncthreads();

    // w4-dot tail: 8x ds_read_b128 per thread, identical summation order
    const int row = tid >> 2;
    const int qd  = tid & 3;
    const short* tp = &sT[row * S2 + qd * 64];
    const float* w4p = w4 + qd * 128;
    float s0 = 0.f, s1 = 0.f;
    #pragma unroll
    for (int c8 = 0; c8 < 8; ++c8) {
        const uint4 v = *(const uint4*)(tp + c8 * 8);
        float av[8];
        av[0] = bflo(v.x); av[1] = bfhi(v.x);
        av[2] = bflo(v.y); av[3] = bfhi(v.y);
        av[4] = bflo(v.z); av[5] = bfhi(v.z);
        av[6] = bflo(v.w); av[7] = bfhi(v.w);
        const float2* wp = (const float2*)(w4p + c8 * 16);
        #pragma unroll
        for (int k = 0; k < 8; ++k) {
            const float2 w = wp[k];
            s0 = fmaf(av[k], w.x, s0);
            s1 = fmaf(av[k], w.y, s1);
        }
    }
    s0 += __shfl_down(s0, 2, 4);  s1 += __shfl_down(s1, 2, 4);
    s0 += __shfl_down(s0, 1, 4);  s1 += __shfl_down(s1, 1, 4);
    if (qd == 0) {
        const int rg = tm + row;
        if (rg < M) {
            s0 += b4[0];
            s1 += b4[1];
            const float m = fmaxf(s0, s1);
            const float l = logf(__expf(s0 - m) + __expf(s1 - m));
            float2 o;
            o.x = s0 - m - l;
            o.y = s1 - m - l;
            *(float2*)(out + (size_t)rg * 2) = o;
        }
    }
}

extern "C" void kernel_launch(void* const* d_in, const int* in_sizes, int n_in,
                              void* d_out, int out_size, void* d_ws, size_t ws_size,
                              hipStream_t stream)
{
    const float* x  = (const float*)d_in[0];
    const int*   ei = (const int*)d_in[1];
    const float* w1 = (const float*)d_in[2];
    const float* b1 = (const float*)d_in[3];
    const float* w2 = (const float*)d_in[4];
    const float* b2 = (const float*)d_in[5];
    const float* w3 = (const float*)d_in[6];
    const float* b3 = (const float*)d_in[7];
    const float* w4 = (const float*)d_in[8];
    const float* b4 = (const float*)d_in[9];

    const int DIN = 128, DH = 256;
    const int M = in_sizes[0] / DIN;   // 50000
    const int E = in_sizes[1] / 2;     // 600000
    const int* src = ei;
    const int* dst = ei + E;
    const int nB = (M + 1023) / 1024;  // <= 64

    // -------- workspace layout --------
    int* deg    = (int*)d_ws;          // M
    int* bsum   = deg + M;             // 64
    int* cur    = bsum + 64;           // M
    int* rowptr = cur + M;             // M+1
    int* srcs   = rowptr + (M + 1);    // E
    size_t off = ((size_t)(3 * M + 1 + 64 + E) * sizeof(int) + 255) & ~(size_t)255;
    unsigned char* x_q = (unsigned char*)((char*)d_ws + off);  off += (size_t)M * 128;  // M x 128 u8
    off = (off + 255) & ~(size_t)255;
    float* xscale = (float*)((char*)d_ws + off);  off += (size_t)M * 4;
    off = (off + 255) & ~(size_t)255;
    short* h1in = (short*)((char*)d_ws + off);  off += (size_t)M * S1 * 2;    // M x 136 bf16
    off = (off + 255) & ~(size_t)255;
    unsigned char* h1q = (unsigned char*)((char*)d_ws + off);  off += (size_t)M * 256; // M x 256 u8
    off = (off + 255) & ~(size_t)255;
    float* hscale = (float*)((char*)d_ws + off);  off += (size_t)M * 4;
    off = (off + 255) & ~(size_t)255;
    short* h2in = (short*)((char*)d_ws + off);  off += (size_t)M * S2 * 2;    // M x 264 bf16
    off = (off + 255) & ~(size_t)255;
    short* w1t  = (short*)((char*)d_ws + off);  off += (size_t)256 * 128 * 2; // fragment-major
    off = (off + 255) & ~(size_t)255;
    short* w2t  = (short*)((char*)d_ws + off);  off += (size_t)256 * 256 * 2;
    off = (off + 255) & ~(size_t)255;
    short* w3t  = (short*)((char*)d_ws + off);  off += (size_t)256 * 256 * 2;

    // -------- prep --------
    hipMemsetAsync(deg, 0, (size_t)M * sizeof(int), stream);
    const int cB = (M * 32 + 255) / 256;
    const int dB = (E + 255) / 256;
    prep_kernel<<<cB + 192 + dB, 256, 0, stream>>>(
        x, x_q, xscale, w1, w2, w3, w1t, w2t, w3t, dst, deg, M, E, cB);

    // -------- CSR build --------
    block_sum_kernel<<<nB, 256, 0, stream>>>(deg, bsum, M);
    scan_blocks2_kernel<<<nB, 256, 0, stream>>>(deg, bsum, rowptr, cur, M, E, nB);
    fill_kernel<<<dB, 256, 0, stream>>>(src, dst, cur, srcs, E);

    const int nblk = (M + 63) / 64;

    // -------- layer 1 --------
    gather_add_d128q<<<(M + 3) / 4, 256, 0, stream>>>(x_q, xscale, rowptr, srcs, h1in, M);
    layer1_fused<<<nblk, 256, 0, stream>>>(h1in, w1t, b1, w2t, b2, h1q, hscale, M);

    // -------- layer 2 --------
    gather_add_d256q<<<(M + 3) / 4, 256, 0, stream>>>(h1q, hscale, rowptr, srcs, h2in, M);
    layer2_fused<<<nblk, 256, 0, stream>>>(h2in, w3t, b3, w4, b4, (float*)d_out, M);
}